// Round 16
// baseline (314.949 us; speedup 1.0000x reference)
//
#include <hip/hip_runtime.h>
#include <hip/hip_fp16.h>

// LFM2 short-conv block. Round 16: r15 + (a) bn-major XCD chunking (each XCD's
// resident blocks share a small B-panel that FITS its 4MB L2; FETCH_SIZE showed
// 320MB vs 56MB distinct = B thrash) and (b) stage-burst at P0 + single aged
// VMCNT0 at tile end (stages retire ~3300cy after issue >> 900cy HBM latency),
// barriers kept per phase.

typedef _Float16 f16x8 __attribute__((ext_vector_type(8)));
typedef float    f32x4 __attribute__((ext_vector_type(4)));

#define GLD_LDS16(gsrc, sdst) \
  __builtin_amdgcn_global_load_lds((const __attribute__((address_space(1))) void*)(gsrc), \
                                   (__attribute__((address_space(3))) void*)(sdst), 16, 0, 0)

#define VMCNT0 asm volatile("s_waitcnt vmcnt(0)" ::: "memory")
#define LGKM0  asm volatile("s_waitcnt lgkmcnt(0)" ::: "memory")
#define BAR    __builtin_amdgcn_s_barrier()
#define FENCE  asm volatile("" ::: "memory")   // compiler-only; no instruction

// ---------------- fused fp32 -> fp16 convert; W_in rows PERMUTED ----------------
// Permutation (dst row of Wih): r<2048 (Bg_h)->2r ; 2048..4095 (Cg)->r+2048 ;
// r>=4096 (x_h)->2(r-4096)+1.
__global__ __launch_bounds__(256) void cvt_all(const float* __restrict__ X,
                                               const float* __restrict__ Wi,
                                               const float* __restrict__ Wo,
                                               _Float16* __restrict__ Xh,
                                               _Float16* __restrict__ Wih,
                                               _Float16* __restrict__ Woh) {
  int base = (blockIdx.x * 256 + threadIdx.x) * 8;   // total 33,554,432 elems
  const float* src;
  _Float16* dst;
  if (base < 16777216) {
    src = X + base; dst = Xh + base;
  } else if (base < 29360128) {
    int off = base - 16777216;
    int row = off >> 11, col = off & 2047;
    int rd = (row < 2048) ? (row << 1) : (row < 4096 ? row + 2048 : (((row - 4096) << 1) | 1));
    src = Wi + off; dst = Wih + rd * 2048 + col;
  } else {
    int off = base - 29360128;
    src = Wo + off; dst = Woh + off;
  }
  const float4* p = reinterpret_cast<const float4*>(src);
  float4 a = p[0], b = p[1];
  f16x8 o;
  o[0] = (_Float16)a.x; o[1] = (_Float16)a.y; o[2] = (_Float16)a.z; o[3] = (_Float16)a.w;
  o[4] = (_Float16)b.x; o[5] = (_Float16)b.y; o[6] = (_Float16)b.z; o[7] = (_Float16)b.w;
  *reinterpret_cast<f16x8*>(dst) = o;
}

// ---------------- conv + Cg gating: y = Cg * causal_conv3(Bx) ----------------
__global__ __launch_bounds__(256) void conv_gate2(const _Float16* __restrict__ Bx,
                                                  const _Float16* __restrict__ Cgb,
                                                  const float* __restrict__ Wc,   // [2048,1,3]
                                                  _Float16* __restrict__ Y) {
  const int h0 = threadIdx.x * 8;
  const int r0 = blockIdx.x * 8;
  const int s0 = r0 & 4095;

  float w0[8], w1[8], w2[8];
#pragma unroll
  for (int j = 0; j < 8; ++j) {
    w0[j] = Wc[(h0 + j) * 3 + 0];
    w1[j] = Wc[(h0 + j) * 3 + 1];
    w2[j] = Wc[(h0 + j) * 3 + 2];
  }

  float bxm2[8] = {}, bxm1[8] = {};
  if (s0 != 0) {
    f16x8 b2 = *reinterpret_cast<const f16x8*>(Bx + (size_t)(r0 - 2) * 2048 + h0);
    f16x8 b1 = *reinterpret_cast<const f16x8*>(Bx + (size_t)(r0 - 1) * 2048 + h0);
#pragma unroll
    for (int j = 0; j < 8; ++j) { bxm2[j] = (float)b2[j]; bxm1[j] = (float)b1[j]; }
  }

  for (int i = 0; i < 8; ++i) {
    f16x8 bxv = *reinterpret_cast<const f16x8*>(Bx  + (size_t)(r0 + i) * 2048 + h0);
    f16x8 cgv = *reinterpret_cast<const f16x8*>(Cgb + (size_t)(r0 + i) * 2048 + h0);
    f16x8 o;
#pragma unroll
    for (int j = 0; j < 8; ++j) {
      float bx   = (float)bxv[j];
      float conv = w0[j] * bxm2[j] + w1[j] * bxm1[j] + w2[j] * bx;
      o[j] = (_Float16)((float)cgv[j] * conv);
      bxm2[j] = bxm1[j];
      bxm1[j] = bx;
    }
    *reinterpret_cast<f16x8*>(Y + (size_t)(r0 + i) * 2048 + h0) = o;
  }
}

// ---------------- fragment load helpers ----------------
__device__ __forceinline__ void ldA(f16x8 (&af)[4][2], const _Float16* p, int base, int ak0, int ak1) {
#pragma unroll
  for (int i = 0; i < 4; ++i) {
    af[i][0] = *(const f16x8*)(p + base + i * 1024 + ak0);
    af[i][1] = *(const f16x8*)(p + base + i * 1024 + ak1);
  }
}
__device__ __forceinline__ void ldB(f16x8 (&bf)[2][2], const _Float16* p, int base, int ak0, int ak1) {
#pragma unroll
  for (int j = 0; j < 2; ++j) {
    bf[j][0] = *(const f16x8*)(p + base + j * 1024 + ak0);
    bf[j][1] = *(const f16x8*)(p + base + j * 1024 + ak1);
  }
}
template <int QM, int QN>
__device__ __forceinline__ void mfmaQ(f32x4 (&acc)[8][4], const f16x8 (&af)[4][2], const f16x8 (&bf)[2][2]) {
  __builtin_amdgcn_s_setprio(1);
#pragma unroll
  for (int i = 0; i < 4; ++i)
#pragma unroll
    for (int j = 0; j < 2; ++j)
#pragma unroll
      for (int ks = 0; ks < 2; ++ks)
        acc[QM * 4 + i][QN * 2 + j] =
            __builtin_amdgcn_mfma_f32_16x16x32_f16(af[i][ks], bf[j][ks], acc[QM * 4 + i][QN * 2 + j], 0, 0, 0);
  __builtin_amdgcn_s_setprio(0);
}

// 256x256 NT GEMM. Stage-burst schedule: all 8 DMA units of tile t+1 issued at P0
// of tile t; single VMCNT0 at P3 end (aged ~3 phases); per-phase barriers kept.
// bn-MAJOR XCD chunking: consecutive swz share a B-panel -> per-XCD B working set
// 1-3MB fits the 4MB L2 (was: full 24MB B streamed -> 320MB FETCH).
// MODE 0: plain CT stores. MODE 1 (GEMM1): paired Bg/x cols -> Bx via shfl_xor;
// Cg region stored separately (see r15).
// ARGS: N = B/C logical col count, K = reduction dim, nbm = M/256, nbn = N/256.
template <typename CT, int MODE>
__global__ __launch_bounds__(512, 2) void gemm8p(const _Float16* __restrict__ Ag,
                                                 const _Float16* __restrict__ Bg,
                                                 CT* __restrict__ Cg_out,
                                                 _Float16* __restrict__ BxP,
                                                 _Float16* __restrict__ CgP,
                                                 int N, int K, int nbm) {
  __shared__ __align__(16) char smem[131072];
  const int tid = threadIdx.x, lane = tid & 63, w = tid >> 6;
  const int wr = w >> 2, wc = w & 3;

  // T1: XCD-bijective swizzle, bn-MAJOR decode (consecutive swz share bn panel)
  const int nwg = (int)gridDim.x, q8 = nwg >> 3;
  const int swz = ((int)blockIdx.x & 7) * q8 + ((int)blockIdx.x >> 3);
  const int bm = (swz % nbm) << 8, bn = (swz / nbm) << 8;

  _Float16* const A0 = (_Float16*)(smem);
  _Float16* const B0 = (_Float16*)(smem + 32768);
  _Float16* const A1 = (_Float16*)(smem + 65536);
  _Float16* const B1 = (_Float16*)(smem + 98304);

  const int rr = tid >> 3;
  const int sCol = ((tid & 7) ^ (rr & 7)) * 8;                  // inverse-swizzled source chunk
  const _Float16* aSrc = Ag + (size_t)(bm + rr) * K + sCol;
  const _Float16* bSrc = Bg + (size_t)(bn + (rr >> 5) * 64 + (rr & 31)) * K + sCol;

  const int ak0 = ((lane >> 4) ^ (lane & 7)) * 8;
  const int ak1 = (((lane >> 4) + 4) ^ (lane & 7)) * 8;
  const int aRB = (wr * 128 + (lane & 15)) * 64;
  const int bRB = (wc * 32 + (lane & 15)) * 64;

  const int nt = K >> 6;

#define STG_A(NBO, kt, u) GLD_LDS16(aSrc + (size_t)(u) * 64 * K + (kt) * 64, \
                                    smem + (NBO) + (u) * 8192 + tid * 16)
#define STG_B(NBO, kt, u) GLD_LDS16(bSrc + (size_t)(((u) & 1) * 128 + ((u) >> 1) * 32) * K + (kt) * 64, \
                                    smem + (NBO) + 32768 + (u) * 8192 + tid * 16)

  f16x8 af[4][2], bf[2][2];
  f32x4 acc[8][4] = {};

  // prologue: stage tile 0 -> buffer 0
  STG_A(0, 0, 0); STG_A(0, 0, 2);
  STG_B(0, 0, 0); STG_B(0, 0, 1);
  STG_B(0, 0, 2); STG_B(0, 0, 3);
  STG_A(0, 0, 1); STG_A(0, 0, 3);
  VMCNT0; BAR; FENCE;

  // Per tile: P0 stages ALL 8 units of tile t+1 (burst); P3 ends with the single
  // aged VMCNT0 + boundary barrier that publishes the next buffer.
#define TILE(AB, BB, NBO, t)                                       \
  {                                                                \
    const int tn = ((t) + 1 < nt) ? (t) + 1 : nt - 1;              \
    /* P0: q=(0,0) + stage burst */                                \
    ldA(af, AB, aRB, ak0, ak1);                                    \
    ldB(bf, BB, bRB, ak0, ak1);                                    \
    STG_A(NBO, tn, 0); STG_A(NBO, tn, 2);                          \
    STG_B(NBO, tn, 0); STG_B(NBO, tn, 1);                          \
    STG_B(NBO, tn, 2); STG_B(NBO, tn, 3);                          \
    STG_A(NBO, tn, 1); STG_A(NBO, tn, 3);                          \
    BAR; FENCE;                                                    \
    mfmaQ<0, 0>(acc, af, bf);                                      \
    /* P1: q=(0,1) */                                              \
    ldB(bf, BB, bRB + 8192, ak0, ak1);                             \
    BAR; FENCE;                                                    \
    mfmaQ<0, 1>(acc, af, bf);                                      \
    /* P2: q=(1,1) */                                              \
    ldA(af, AB, aRB + 4096, ak0, ak1);                             \
    BAR; FENCE;                                                    \
    mfmaQ<1, 1>(acc, af, bf);                                      \
    /* P3: q=(1,0), re-read B half 0; aged drain + boundary barrier */ \
    ldB(bf, BB, bRB, ak0, ak1);                                    \
    VMCNT0; BAR; FENCE;                                            \
    mfmaQ<1, 0>(acc, af, bf);                                      \
  }

  for (int t = 0; t < nt; t += 2) {
    TILE(A0, B0, 65536, t);
    TILE(A1, B1, 0, t + 1);
  }
  LGKM0; VMCNT0;

  // epilogue: D row=(lane>>4)*4+reg, col=lane&15
  const int rb  = bm + wr * 128 + ((lane >> 4) << 2);
  const int cbl = bn + wc * 64 + (lane & 15);
  if (MODE == 0) {
#pragma unroll
    for (int mi = 0; mi < 8; ++mi)
#pragma unroll
      for (int nj = 0; nj < 4; ++nj) {
        f32x4 v = acc[mi][nj];
#pragma unroll
        for (int rg = 0; rg < 4; ++rg)
          Cg_out[(size_t)(rb + mi * 16 + rg) * N + cbl + nj * 16] = (CT)v[rg];
      }
  } else if (bn < 4096) {
    // paired region: col 2h = Bg_h, 2h+1 = x_h (lane parity = col parity)
    const bool writer = ((lane & 1) == 0);
#pragma unroll
    for (int mi = 0; mi < 8; ++mi)
#pragma unroll
      for (int nj = 0; nj < 4; ++nj) {
        f32x4 v = acc[mi][nj];
        const int h = (cbl + nj * 16) >> 1;
#pragma unroll
        for (int rg = 0; rg < 4; ++rg) {
          float part = __shfl_xor(v[rg], 1);
          float p = v[rg] * part;
          if (writer)
            BxP[(size_t)(rb + mi * 16 + rg) * 2048 + h] = (_Float16)p;
        }
      }
  } else {
    const int hc = cbl - 4096;
#pragma unroll
    for (int mi = 0; mi < 8; ++mi)
#pragma unroll
      for (int nj = 0; nj < 4; ++nj) {
        f32x4 v = acc[mi][nj];
#pragma unroll
        for (int rg = 0; rg < 4; ++rg)
          CgP[(size_t)(rb + mi * 16 + rg) * 2048 + hc + nj * 16] = (_Float16)v[rg];
      }
  }
#undef TILE
#undef STG_A
#undef STG_B
}

// ---------------- launcher ----------------
extern "C" void kernel_launch(void* const* d_in, const int* in_sizes, int n_in,
                              void* d_out, int out_size, void* d_ws, size_t ws_size,
                              hipStream_t stream) {
  const float* X  = (const float*)d_in[0];  // [2,4096,2048]
  const float* Wi = (const float*)d_in[1];  // [6144,2048]
  const float* Wc = (const float*)d_in[2];  // [2048,1,3]
  const float* Wo = (const float*)d_in[3];  // [2048,2048]
  float* out = (float*)d_out;               // [2,4096,2048] fp32

  char* ws = (char*)d_ws;
  _Float16* Xh  = (_Float16*)(ws);                     // 33,554,432 B
  _Float16* Wih = (_Float16*)(ws + 33554432);          // 25,165,824 B (permuted rows)
  _Float16* Woh = (_Float16*)(ws + 58720256);          //  8,388,608 B
  _Float16* Bx  = (_Float16*)(ws + 67108864);          // 33,554,432 B
  _Float16* CgB = (_Float16*)(ws + 100663296);         // 33,554,432 B
  _Float16* Yh  = (_Float16*)(ws + 134217728);         // 33,554,432 B -> 167,772,160 total
  (void)ws_size; (void)in_sizes; (void)n_in; (void)out_size;

  cvt_all<<<dim3(16384), 256, 0, stream>>>(X, Wi, Wo, Xh, Wih, Woh);

  // in_proj (+gate fusion): writes Bx[8192,2048] and Cg[8192,2048] fp16
  gemm8p<_Float16, 1><<<dim3(768), 512, 0, stream>>>(Xh, Wih, Bx, Bx, CgB, 6144, 2048, 32);

  conv_gate2<<<dim3(1024), 256, 0, stream>>>(Bx, CgB, Wc, Yh);

  // out_proj: [8192,2048] x [2048,2048]^T -> out fp32
  gemm8p<float, 0><<<dim3(256), 512, 0, stream>>>(Yh, Woh, out, nullptr, nullptr, 2048, 2048, 32);
}

// Round 17
// 289.455 us; speedup vs baseline: 1.0881x; 1.0881x over previous
//
#include <hip/hip_runtime.h>
#include <hip/hip_fp16.h>

// LFM2 short-conv block. Round 17: r15 core (best, 293.4us) + 2D XCD chunking:
// each XCD owns a 4bm x nbn rectangle traversed in 4bm x 8bn sub-rectangles of 32
// blocks, so the ~32 concurrently-resident blocks per XCD share a 4MB A-panel and
// an 8MB B-panel (was: 2MB A + 24MB B streaming through the 4MB L2; FETCH 320MB).
// r16's bn-major decode (A-thrash, FETCH 405MB) and stage-burst are reverted.

typedef _Float16 f16x8 __attribute__((ext_vector_type(8)));
typedef float    f32x4 __attribute__((ext_vector_type(4)));

#define GLD_LDS16(gsrc, sdst) \
  __builtin_amdgcn_global_load_lds((const __attribute__((address_space(1))) void*)(gsrc), \
                                   (__attribute__((address_space(3))) void*)(sdst), 16, 0, 0)

#define VMCNT4 asm volatile("s_waitcnt vmcnt(4)" ::: "memory")
#define VMCNT0 asm volatile("s_waitcnt vmcnt(0)" ::: "memory")
#define LGKM0  asm volatile("s_waitcnt lgkmcnt(0)" ::: "memory")
#define BAR    __builtin_amdgcn_s_barrier()
#define FENCE  asm volatile("" ::: "memory")   // compiler-only; no instruction

// ---------------- fused fp32 -> fp16 convert; W_in rows PERMUTED ----------------
// Permutation (dst row of Wih): r<2048 (Bg_h)->2r ; 2048..4095 (Cg)->r+2048 ;
// r>=4096 (x_h)->2(r-4096)+1.
__global__ __launch_bounds__(256) void cvt_all(const float* __restrict__ X,
                                               const float* __restrict__ Wi,
                                               const float* __restrict__ Wo,
                                               _Float16* __restrict__ Xh,
                                               _Float16* __restrict__ Wih,
                                               _Float16* __restrict__ Woh) {
  int base = (blockIdx.x * 256 + threadIdx.x) * 8;   // total 33,554,432 elems
  const float* src;
  _Float16* dst;
  if (base < 16777216) {
    src = X + base; dst = Xh + base;
  } else if (base < 29360128) {
    int off = base - 16777216;
    int row = off >> 11, col = off & 2047;
    int rd = (row < 2048) ? (row << 1) : (row < 4096 ? row + 2048 : (((row - 4096) << 1) | 1));
    src = Wi + off; dst = Wih + rd * 2048 + col;
  } else {
    int off = base - 29360128;
    src = Wo + off; dst = Woh + off;
  }
  const float4* p = reinterpret_cast<const float4*>(src);
  float4 a = p[0], b = p[1];
  f16x8 o;
  o[0] = (_Float16)a.x; o[1] = (_Float16)a.y; o[2] = (_Float16)a.z; o[3] = (_Float16)a.w;
  o[4] = (_Float16)b.x; o[5] = (_Float16)b.y; o[6] = (_Float16)b.z; o[7] = (_Float16)b.w;
  *reinterpret_cast<f16x8*>(dst) = o;
}

// ---------------- conv + Cg gating: y = Cg * causal_conv3(Bx) ----------------
__global__ __launch_bounds__(256) void conv_gate2(const _Float16* __restrict__ Bx,
                                                  const _Float16* __restrict__ Cgb,
                                                  const float* __restrict__ Wc,   // [2048,1,3]
                                                  _Float16* __restrict__ Y) {
  const int h0 = threadIdx.x * 8;
  const int r0 = blockIdx.x * 8;
  const int s0 = r0 & 4095;

  float w0[8], w1[8], w2[8];
#pragma unroll
  for (int j = 0; j < 8; ++j) {
    w0[j] = Wc[(h0 + j) * 3 + 0];
    w1[j] = Wc[(h0 + j) * 3 + 1];
    w2[j] = Wc[(h0 + j) * 3 + 2];
  }

  float bxm2[8] = {}, bxm1[8] = {};
  if (s0 != 0) {
    f16x8 b2 = *reinterpret_cast<const f16x8*>(Bx + (size_t)(r0 - 2) * 2048 + h0);
    f16x8 b1 = *reinterpret_cast<const f16x8*>(Bx + (size_t)(r0 - 1) * 2048 + h0);
#pragma unroll
    for (int j = 0; j < 8; ++j) { bxm2[j] = (float)b2[j]; bxm1[j] = (float)b1[j]; }
  }

  for (int i = 0; i < 8; ++i) {
    f16x8 bxv = *reinterpret_cast<const f16x8*>(Bx  + (size_t)(r0 + i) * 2048 + h0);
    f16x8 cgv = *reinterpret_cast<const f16x8*>(Cgb + (size_t)(r0 + i) * 2048 + h0);
    f16x8 o;
#pragma unroll
    for (int j = 0; j < 8; ++j) {
      float bx   = (float)bxv[j];
      float conv = w0[j] * bxm2[j] + w1[j] * bxm1[j] + w2[j] * bx;
      o[j] = (_Float16)((float)cgv[j] * conv);
      bxm2[j] = bxm1[j];
      bxm1[j] = bx;
    }
    *reinterpret_cast<f16x8*>(Y + (size_t)(r0 + i) * 2048 + h0) = o;
  }
}

// ---------------- fragment load helpers ----------------
__device__ __forceinline__ void ldA(f16x8 (&af)[4][2], const _Float16* p, int base, int ak0, int ak1) {
#pragma unroll
  for (int i = 0; i < 4; ++i) {
    af[i][0] = *(const f16x8*)(p + base + i * 1024 + ak0);
    af[i][1] = *(const f16x8*)(p + base + i * 1024 + ak1);
  }
}
__device__ __forceinline__ void ldB(f16x8 (&bf)[2][2], const _Float16* p, int base, int ak0, int ak1) {
#pragma unroll
  for (int j = 0; j < 2; ++j) {
    bf[j][0] = *(const f16x8*)(p + base + j * 1024 + ak0);
    bf[j][1] = *(const f16x8*)(p + base + j * 1024 + ak1);
  }
}
template <int QM, int QN>
__device__ __forceinline__ void mfmaQ(f32x4 (&acc)[8][4], const f16x8 (&af)[4][2], const f16x8 (&bf)[2][2]) {
  __builtin_amdgcn_s_setprio(1);
#pragma unroll
  for (int i = 0; i < 4; ++i)
#pragma unroll
    for (int j = 0; j < 2; ++j)
#pragma unroll
      for (int ks = 0; ks < 2; ++ks)
        acc[QM * 4 + i][QN * 2 + j] =
            __builtin_amdgcn_mfma_f32_16x16x32_f16(af[i][ks], bf[j][ks], acc[QM * 4 + i][QN * 2 + j], 0, 0, 0);
  __builtin_amdgcn_s_setprio(0);
}

// 256x256 NT GEMM (r13/r15 core, staggered vmcnt(4) schedule).
// 2D XCD chunking: xcd = bid&7, i = bid>>3; bm = xcd*4 + (i&31)>>3,
// bn = (i>>5)*8 + (i&7). Bijective for grid in {256,768} with nbm=32, nbn%8==0.
// The ~32 concurrently-resident blocks of an XCD form a 4bm x 8bn rectangle:
// shared working set 4MB A + 8MB B (vs 2+24 streaming before).
// MODE 0: plain CT stores. MODE 1 (GEMM1): paired Bg/x cols -> Bx via shfl_xor;
// Cg region (bn>=4096) stored separately.
template <typename CT, int MODE>
__global__ __launch_bounds__(512, 2) void gemm8p(const _Float16* __restrict__ Ag,
                                                 const _Float16* __restrict__ Bg,
                                                 CT* __restrict__ Cg_out,
                                                 _Float16* __restrict__ BxP,
                                                 _Float16* __restrict__ CgP,
                                                 int N, int K) {
  __shared__ __align__(16) char smem[131072];
  const int tid = threadIdx.x, lane = tid & 63, w = tid >> 6;
  const int wr = w >> 2, wc = w & 3;

  // 2D XCD chunking (see header comment)
  const int xcd = (int)blockIdx.x & 7;
  const int i4  = (int)blockIdx.x >> 3;
  const int bm = (((xcd << 2) + ((i4 & 31) >> 3))) << 8;
  const int bn = ((((i4 >> 5) << 3)) + (i4 & 7)) << 8;

  _Float16* const A0 = (_Float16*)(smem);
  _Float16* const B0 = (_Float16*)(smem + 32768);
  _Float16* const A1 = (_Float16*)(smem + 65536);
  _Float16* const B1 = (_Float16*)(smem + 98304);

  const int rr = tid >> 3;
  const int sCol = ((tid & 7) ^ (rr & 7)) * 8;                  // inverse-swizzled source chunk
  const _Float16* aSrc = Ag + (size_t)(bm + rr) * K + sCol;
  const _Float16* bSrc = Bg + (size_t)(bn + (rr >> 5) * 64 + (rr & 31)) * K + sCol;

  const int ak0 = ((lane >> 4) ^ (lane & 7)) * 8;
  const int ak1 = (((lane >> 4) + 4) ^ (lane & 7)) * 8;
  const int aRB = (wr * 128 + (lane & 15)) * 64;
  const int bRB = (wc * 32 + (lane & 15)) * 64;

  const int nt = K >> 6;

#define STG_A(NBO, kt, u) GLD_LDS16(aSrc + (size_t)(u) * 64 * K + (kt) * 64, \
                                    smem + (NBO) + (u) * 8192 + tid * 16)
#define STG_B(NBO, kt, u) GLD_LDS16(bSrc + (size_t)(((u) & 1) * 128 + ((u) >> 1) * 32) * K + (kt) * 64, \
                                    smem + (NBO) + 32768 + (u) * 8192 + tid * 16)

  f16x8 af[4][2], bf[2][2];
  f32x4 acc[8][4] = {};

  STG_A(0, 0, 0); STG_A(0, 0, 2);
  STG_B(0, 0, 0); STG_B(0, 0, 1);
  STG_B(0, 0, 2); STG_B(0, 0, 3);
  STG_A(0, 0, 1); STG_A(0, 0, 3);
  VMCNT4; BAR; FENCE;

#define TILE(AB, BB, NBO, t)                                       \
  {                                                                \
    const int tn = ((t) + 1 < nt) ? (t) + 1 : nt - 1;              \
    ldA(af, AB, aRB, ak0, ak1);                                    \
    ldB(bf, BB, bRB, ak0, ak1);                                    \
    STG_A(NBO, tn, 0); STG_A(NBO, tn, 2);                          \
    VMCNT4; BAR; FENCE;                                            \
    mfmaQ<0, 0>(acc, af, bf);                                      \
    ldB(bf, BB, bRB + 8192, ak0, ak1);                             \
    STG_B(NBO, tn, 0); STG_B(NBO, tn, 1);                          \
    VMCNT4; BAR; FENCE;                                            \
    mfmaQ<0, 1>(acc, af, bf);                                      \
    ldA(af, AB, aRB + 4096, ak0, ak1);                             \
    STG_B(NBO, tn, 2); STG_B(NBO, tn, 3);                          \
    BAR; FENCE;                                                    \
    mfmaQ<1, 1>(acc, af, bf);                                      \
    ldB(bf, BB, bRB, ak0, ak1);                                    \
    STG_A(NBO, tn, 1); STG_A(NBO, tn, 3);                          \
    VMCNT4; BAR; FENCE;                                            \
    mfmaQ<1, 0>(acc, af, bf);                                      \
  }

  for (int t = 0; t < nt; t += 2) {
    TILE(A0, B0, 65536, t);
    TILE(A1, B1, 0, t + 1);
  }
  LGKM0; VMCNT0;

  // epilogue: D row=(lane>>4)*4+reg, col=lane&15
  const int rb  = bm + wr * 128 + ((lane >> 4) << 2);
  const int cbl = bn + wc * 64 + (lane & 15);
  if (MODE == 0) {
#pragma unroll
    for (int mi = 0; mi < 8; ++mi)
#pragma unroll
      for (int nj = 0; nj < 4; ++nj) {
        f32x4 v = acc[mi][nj];
#pragma unroll
        for (int rg = 0; rg < 4; ++rg)
          Cg_out[(size_t)(rb + mi * 16 + rg) * N + cbl + nj * 16] = (CT)v[rg];
      }
  } else if (bn < 4096) {
    // paired region: col 2h = Bg_h, 2h+1 = x_h (lane parity = col parity)
    const bool writer = ((lane & 1) == 0);
#pragma unroll
    for (int mi = 0; mi < 8; ++mi)
#pragma unroll
      for (int nj = 0; nj < 4; ++nj) {
        f32x4 v = acc[mi][nj];
        const int h = (cbl + nj * 16) >> 1;
#pragma unroll
        for (int rg = 0; rg < 4; ++rg) {
          float part = __shfl_xor(v[rg], 1);
          float p = v[rg] * part;
          if (writer)
            BxP[(size_t)(rb + mi * 16 + rg) * 2048 + h] = (_Float16)p;
        }
      }
  } else {
    const int hc = cbl - 4096;
#pragma unroll
    for (int mi = 0; mi < 8; ++mi)
#pragma unroll
      for (int nj = 0; nj < 4; ++nj) {
        f32x4 v = acc[mi][nj];
#pragma unroll
        for (int rg = 0; rg < 4; ++rg)
          CgP[(size_t)(rb + mi * 16 + rg) * 2048 + hc + nj * 16] = (_Float16)v[rg];
      }
  }
#undef TILE
#undef STG_A
#undef STG_B
}

// ---------------- launcher ----------------
extern "C" void kernel_launch(void* const* d_in, const int* in_sizes, int n_in,
                              void* d_out, int out_size, void* d_ws, size_t ws_size,
                              hipStream_t stream) {
  const float* X  = (const float*)d_in[0];  // [2,4096,2048]
  const float* Wi = (const float*)d_in[1];  // [6144,2048]
  const float* Wc = (const float*)d_in[2];  // [2048,1,3]
  const float* Wo = (const float*)d_in[3];  // [2048,2048]
  float* out = (float*)d_out;               // [2,4096,2048] fp32

  char* ws = (char*)d_ws;
  _Float16* Xh  = (_Float16*)(ws);                     // 33,554,432 B
  _Float16* Wih = (_Float16*)(ws + 33554432);          // 25,165,824 B (permuted rows)
  _Float16* Woh = (_Float16*)(ws + 58720256);          //  8,388,608 B
  _Float16* Bx  = (_Float16*)(ws + 67108864);          // 33,554,432 B
  _Float16* CgB = (_Float16*)(ws + 100663296);         // 33,554,432 B
  _Float16* Yh  = (_Float16*)(ws + 134217728);         // 33,554,432 B -> 167,772,160 total
  (void)ws_size; (void)in_sizes; (void)n_in; (void)out_size;

  cvt_all<<<dim3(16384), 256, 0, stream>>>(X, Wi, Wo, Xh, Wih, Woh);

  // in_proj (+gate fusion): writes Bx[8192,2048] and Cg[8192,2048] fp16
  gemm8p<_Float16, 1><<<dim3(768), 512, 0, stream>>>(Xh, Wih, Bx, Bx, CgB, 6144, 2048);

  conv_gate2<<<dim3(1024), 256, 0, stream>>>(Bx, CgB, Wc, Yh);

  // out_proj: [8192,2048] x [2048,2048]^T -> out fp32
  gemm8p<float, 0><<<dim3(256), 512, 0, stream>>>(Yh, Woh, out, nullptr, nullptr, 2048, 2048);
}